// Round 1
// baseline (935.254 us; speedup 1.0000x reference)
//
#include <hip/hip_runtime.h>
#include <hip/hip_bf16.h>

typedef __attribute__((ext_vector_type(8))) short short8;
typedef __attribute__((ext_vector_type(4))) float f32x4;

#define D_DIM 256
#define G_DIM 256
#define NSEG 4096
#define BM 64
#define PBLK 256  // persistent blocks, 1 per CU

__device__ __forceinline__ unsigned f2bf_u(float f) {
  unsigned u = __builtin_bit_cast(unsigned, f);
  return (u + 0x7fffu + ((u >> 16) & 1u)) >> 16;   // RNE, inputs are finite
}
__device__ __forceinline__ unsigned pk_bf2(float a, float b) {
  __hip_bfloat162 h = __float22bfloat162_rn(float2{a, b});  // v_cvt_pk_bf16_f32
  unsigned r;
  __builtin_memcpy(&r, &h, 4);
  return r;
}

// ---- W/Wg -> bf16, transposed: Wc[j][k] = (j<256 ? W[k][j] : Wg[k][j-256]) ----
__global__ void wconv_kernel(const float* __restrict__ W, const float* __restrict__ Wg,
                             unsigned short* __restrict__ Wc) {
  int j = blockIdx.x;          // 0..511
  int k = threadIdx.x;         // 0..255
  float v = (j < 256) ? W[k * 256 + j] : Wg[k * 256 + (j - 256)];
  Wc[j * 256 + k] = (unsigned short)f2bf_u(v);
}

// ---- counts per segment via binary search (batch is sorted) ----
__global__ void count_kernel(const int* __restrict__ batch, int N, float* __restrict__ counts) {
  int g = blockIdx.x * blockDim.x + threadIdx.x;
  if (g >= NSEG) return;
  int lo = 0, hi = N;
  while (lo < hi) { int mid = (lo + hi) >> 1; if (batch[mid] < g) lo = mid + 1; else hi = mid; }
  int lo2 = lo, hi2 = N;
  while (lo2 < hi2) { int mid = (lo2 + hi2) >> 1; if (batch[mid] < g + 1) lo2 = mid + 1; else hi2 = mid; }
  counts[g] = (float)(lo2 - lo);
}

// ---- fused: dual GEMM (states|gates) -> softmax gate -> segment partial sums ----
// Persistent: 256 blocks x 1024 thr (16 waves), 1 block/CU. Wave w owns 16-col pair
// (states col cb..cb+16, gates col 256+cb..). acc[4][2]=32 AGPR -> room for:
//   - x-tile double buffer: next tile's 4 float4/thread issued a full tile early
//   - B-frag rolling prefetch depth 2 (B cols identical every tile -> L2-hot)
__global__ __launch_bounds__(1024, 4) void fused_main(
    const float* __restrict__ x, const int* __restrict__ batch,
    const unsigned short* __restrict__ Wc,
    const float* __restrict__ bvec, const float* __restrict__ bgvec,
    float* __restrict__ seg, int N) {
  __shared__ __align__(16) char xs[2][32768];     // x tile [64][256] bf16, swizzled, dbuf
  __shared__ __align__(16) float part[16][64];    // per-wave row partial sums
  __shared__ __align__(16) float sinv[64];        // 1/rowsum

  const int t = threadIdx.x;
  const int lane = t & 63;
  const int wid = t >> 6;        // 0..15
  const int lr = lane & 15;
  const int lk = lane >> 4;
  const int cb = wid * 16;
  const int ntiles = N / BM;     // 15625

  // staging addressing: 2 rows of 8 floats per thread (rows srl, srl+32)
  const int srl = t >> 5;              // 0..31
  const int skb = (t & 31) * 8;        // bf16-elem col base
  const int sby0 = (srl * 512 + skb * 2) ^ ((srl & 7) << 4);
  const int sby1 = ((srl + 32) * 512 + skb * 2) ^ (((srl + 32) & 7) << 4);

  // B pointers: per-wave constant columns, reused every tile (L2-resident)
  const unsigned short* Bs = Wc + (cb + lr) * 256 + lk * 8;          // states col
  const unsigned short* Bg = Wc + (256 + cb + lr) * 256 + lk * 8;    // gates col

  // A-read bases (row*512 bits >=9, disjoint from k-offset bits 4..8 and swizzle bits 4..6)
  int abase[4], asw[4];
#pragma unroll
  for (int m = 0; m < 4; ++m) {
    int ar = m * 16 + lr;
    abase[m] = ar * 512;
    asw[m] = (ar & 7) << 4;
  }
  const int ko2 = lk * 16;

  const float bgv = bgvec[cb + lr];
  const float bv = bvec[cb + lr];

  int tile = blockIdx.x;
  float4 ld0, ld1, ld2, ld3;
  {  // prologue: issue first tile's loads
    const float* p0 = x + (long)(tile * BM + srl) * D_DIM + skb;
    ld0 = ((const float4*)p0)[0];
    ld1 = ((const float4*)p0)[1];
    const float* p1 = p0 + 32 * D_DIM;
    ld2 = ((const float4*)p1)[0];
    ld3 = ((const float4*)p1)[1];
  }

  for (int it = 0; tile < ntiles; ++it, tile += PBLK) {
    char* xb = xs[it & 1];
    const long row0 = (long)tile * BM;

    // stage current tile (consume ld*), then immediately issue next tile's loads
    {
      uint4 pk0, pk1;
      pk0.x = pk_bf2(ld0.x, ld0.y); pk0.y = pk_bf2(ld0.z, ld0.w);
      pk0.z = pk_bf2(ld1.x, ld1.y); pk0.w = pk_bf2(ld1.z, ld1.w);
      pk1.x = pk_bf2(ld2.x, ld2.y); pk1.y = pk_bf2(ld2.z, ld2.w);
      pk1.z = pk_bf2(ld3.x, ld3.y); pk1.w = pk_bf2(ld3.z, ld3.w);
      *(uint4*)(xb + sby0) = pk0;
      *(uint4*)(xb + sby1) = pk1;
    }
    if (tile + PBLK < ntiles) {
      const float* p0 = x + ((long)(tile + PBLK) * BM + srl) * D_DIM + skb;
      ld0 = ((const float4*)p0)[0];
      ld1 = ((const float4*)p0)[1];
      const float* p1 = p0 + 32 * D_DIM;
      ld2 = ((const float4*)p1)[0];
      ld3 = ((const float4*)p1)[1];
    }

    // B rolling prefetch (depth 2), issued under the barrier wait
    short8 bcur0 = *(const short8*)(Bs);
    short8 bcur1 = *(const short8*)(Bg);
    short8 bnxt0 = *(const short8*)(Bs + 32);
    short8 bnxt1 = *(const short8*)(Bg + 32);

    __syncthreads();

    f32x4 acc[4][2];
#pragma unroll
    for (int m = 0; m < 4; ++m) {
      acc[m][0] = (f32x4){0.f, 0.f, 0.f, 0.f};
      acc[m][1] = (f32x4){0.f, 0.f, 0.f, 0.f};
    }

#pragma unroll
    for (int kk = 0; kk < 8; ++kk) {
      short8 a[4];
#pragma unroll
      for (int m = 0; m < 4; ++m)
        a[m] = *(const short8*)(xb + abase[m] + ((kk * 64 + ko2) ^ asw[m]));
      short8 b0 = bcur0, b1 = bcur1;
      bcur0 = bnxt0; bcur1 = bnxt1;
      if (kk < 6) {
        bnxt0 = *(const short8*)(Bs + (kk + 2) * 32);
        bnxt1 = *(const short8*)(Bg + (kk + 2) * 32);
      }
#pragma unroll
      for (int m = 0; m < 4; ++m) {
        acc[m][0] = __builtin_amdgcn_mfma_f32_16x16x32_bf16(a[m], b0, acc[m][0], 0, 0, 0);
        acc[m][1] = __builtin_amdgcn_mfma_f32_16x16x32_bf16(a[m], b1, acc[m][1], 0, 0, 0);
      }
    }

    // gates: e = exp(logit + bg) in place (no max-sub: logits ~N(0,1), exp bounded)
#pragma unroll
    for (int m = 0; m < 4; ++m)
#pragma unroll
      for (int q = 0; q < 4; ++q)
        acc[m][1][q] = __expf(acc[m][1][q] + bgv);

    // wave-local row sums over this wave's 16 gate cols (reduce over lr via shfl)
#pragma unroll
    for (int m = 0; m < 4; ++m) {
      float s[4];
#pragma unroll
      for (int q = 0; q < 4; ++q) {
        float v = acc[m][1][q];
        v += __shfl_xor(v, 1);
        v += __shfl_xor(v, 2);
        v += __shfl_xor(v, 4);
        v += __shfl_xor(v, 8);
        s[q] = v;
      }
      if (lr == 0) {
#pragma unroll
        for (int q = 0; q < 4; ++q) part[wid][m * 16 + lk * 4 + q] = s[q];
      }
    }
    __syncthreads();
    if (wid == 0) {
      float v = 0.f;
#pragma unroll
      for (int w = 0; w < 16; ++w) v += part[w][lane];
      sinv[lane] = 1.0f / v;
    }
    __syncthreads();

    // gating: gated = (states + b) * e * sinv
#pragma unroll
    for (int m = 0; m < 4; ++m) {
      f32x4 siv = *(const f32x4*)(&sinv[m * 16 + lk * 4]);
#pragma unroll
      for (int q = 0; q < 4; ++q)
        acc[m][0][q] = (acc[m][0][q] + bv) * acc[m][1][q] * siv[q];
    }

    // segment reduce: batch sorted -> tile spans [g0, g1] (typically 1-2 segments)
    int rb[4][4];
#pragma unroll
    for (int m = 0; m < 4; ++m) {
      const int4 v = *(const int4*)(batch + row0 + m * 16 + lk * 4);
      rb[m][0] = v.x; rb[m][1] = v.y; rb[m][2] = v.z; rb[m][3] = v.w;
    }
    const int g0 = batch[row0];
    const int g1 = batch[row0 + BM - 1];
    for (int g = g0; g <= g1; ++g) {
      float p = 0.f;
#pragma unroll
      for (int m = 0; m < 4; ++m)
#pragma unroll
        for (int q = 0; q < 4; ++q)
          p += (rb[m][q] == g) ? acc[m][0][q] : 0.f;
      p += __shfl_xor(p, 16);
      p += __shfl_xor(p, 32);
      if (lane < 16) atomicAdd(seg + (long)g * G_DIM + cb + lane, p);
    }
  }
}

// ---- out = (seg/max(cnt,1)) @ Wf + bf, in-place on d_out (block-local staging) ----
__global__ __launch_bounds__(256) void final_kernel(
    float* __restrict__ seg, const float* __restrict__ counts,
    const float* __restrict__ Wf, const float* __restrict__ bfv) {
  __shared__ float mlds[16][257];
  int g0 = blockIdx.x * 16;
  int t = threadIdx.x;
#pragma unroll
  for (int i = 0; i < 16; ++i) {
    float inv = 1.0f / fmaxf(counts[g0 + i], 1.0f);
    mlds[i][t] = seg[(g0 + i) * 256 + t] * inv;
  }
  __syncthreads();
  float a[16];
#pragma unroll
  for (int i = 0; i < 16; ++i) a[i] = 0.f;
  for (int k = 0; k < 256; ++k) {
    float w = Wf[k * 256 + t];
#pragma unroll
    for (int i = 0; i < 16; ++i) a[i] += mlds[i][k] * w;
  }
  float bfx = bfv[t];
#pragma unroll
  for (int i = 0; i < 16; ++i) seg[(g0 + i) * 256 + t] = a[i] + bfx;
}

extern "C" void kernel_launch(void* const* d_in, const int* in_sizes, int n_in,
                              void* d_out, int out_size, void* d_ws, size_t ws_size,
                              hipStream_t stream) {
  const float* x = (const float*)d_in[0];
  const int* batch = (const int*)d_in[1];
  const float* W = (const float*)d_in[2];
  const float* b = (const float*)d_in[3];
  const float* Wg = (const float*)d_in[4];
  const float* bg = (const float*)d_in[5];
  const float* Wf = (const float*)d_in[6];
  const float* bf = (const float*)d_in[7];
  const int N = in_sizes[0] / D_DIM;  // 1,000,000

  unsigned short* Wc = (unsigned short*)d_ws;              // 512*256*2 = 262144 B
  float* counts = (float*)((char*)d_ws + 262144);          // 4096*4 = 16384 B
  float* seg = (float*)d_out;                              // seg_sum scratch == output buffer

  (void)hipMemsetAsync(d_out, 0, (size_t)out_size * sizeof(float), stream);
  hipLaunchKernelGGL(wconv_kernel, dim3(512), dim3(256), 0, stream, W, Wg, Wc);
  hipLaunchKernelGGL(count_kernel, dim3(NSEG / 256), dim3(256), 0, stream, batch, N, counts);
  hipLaunchKernelGGL(fused_main, dim3(PBLK), dim3(1024), 0, stream, x, batch, Wc, b, bg, seg, N);
  hipLaunchKernelGGL(final_kernel, dim3(NSEG / 16), dim3(256), 0, stream, seg, counts, Wf, bf);
}